// Round 4
// baseline (163.140 us; speedup 1.0000x reference)
//
#include <hip/hip_runtime.h>

#define NSEG 16
#define CIN 64
#define COUT 128
#define BN_EPS 1e-5f

typedef float vf4 __attribute__((ext_vector_type(4)));

// ---- index dtype hedge: int64 per reference, but int32 if JAX x64 is off.
// Viewing as int32: element N-1 is 15 (last sorted value) if int32, 0 if int64.
__device__ __forceinline__ bool idx_is64(const void* p, int N) {
    return ((const int*)p)[N - 1] == 0;
}
__device__ __forceinline__ int load_idx(const void* p, long long i, bool is64) {
    return is64 ? (int)((const long long*)p)[i] : ((const int*)p)[i];
}

// ws layout (floats):
//   [0, 1024)        seg_sum[16][64]
//   [1024, 3072)     h_final[16][128]
//   [3072, ...)      bnd[17] as int

// K1: zero seg_sum + 15 binary searches for segment boundaries (sorted idx).
__global__ __launch_bounds__(256) void k_bounds(const void* __restrict__ idx, int N,
                                                float* __restrict__ seg_sum,
                                                int* __restrict__ bnd) {
    const int tid = threadIdx.x;
    for (int i = tid; i < NSEG * CIN; i += 256) seg_sum[i] = 0.0f;
    if (tid <= NSEG) {
        if (tid == 0) bnd[0] = 0;
        else if (tid == NSEG) bnd[NSEG] = N;
        else {
            const bool is64 = idx_is64(idx, N);
            int lo = 0, hi = N;
            while (lo < hi) {
                const int mid = (lo + hi) >> 1;
                if (load_idx(idx, mid, is64) < tid) lo = mid + 1; else hi = mid;
            }
            bnd[tid] = lo;
        }
    }
}

// K2: segment sum. Block owns contiguous rows; boundaries make sub-ranges
// segment-uniform -> inner loop is pure float4 load+add.
__global__ __launch_bounds__(256) void k_segsum(const float* __restrict__ feat,
                                                const int* __restrict__ bnd,
                                                float* __restrict__ seg_sum,
                                                int N, int rows_per_blk) {
    __shared__ float acc_lds[NSEG * CIN];
    __shared__ int sbnd[NSEG + 1];
    const int tid = threadIdx.x;
    if (tid <= NSEG) sbnd[tid] = bnd[tid];
    for (int i = tid; i < NSEG * CIN; i += 256) acc_lds[i] = 0.0f;
    __syncthreads();

    const int row0 = blockIdx.x * rows_per_blk;
    const int row_end = min(row0 + rows_per_blk, N);
    if (row0 < row_end) {
        const int q4 = (tid & 15) * 4;     // float offset in row
        const int lr = tid >> 4;           // 0..15 row phase
        int s = 0;
        while (s < NSEG - 1 && sbnd[s + 1] <= row0) ++s;
        for (; s < NSEG && sbnd[s] < row_end; ++s) {
            const int a = max(sbnd[s], row0);
            const int b = min(sbnd[s + 1], row_end);
            if (a >= b) continue;
            vf4 acc = {0.f, 0.f, 0.f, 0.f};
            #pragma unroll 4
            for (int r = a + lr; r < b; r += 16)
                acc += *(const vf4*)(feat + (size_t)r * CIN + q4);
            atomicAdd(&acc_lds[s * CIN + q4 + 0], acc.x);
            atomicAdd(&acc_lds[s * CIN + q4 + 1], acc.y);
            atomicAdd(&acc_lds[s * CIN + q4 + 2], acc.z);
            atomicAdd(&acc_lds[s * CIN + q4 + 3], acc.w);
        }
    }
    __syncthreads();
    for (int i = tid; i < NSEG * CIN; i += 256) {
        const float v = acc_lds[i];
        if (v != 0.0f) atomicAdd(&seg_sum[i], v);
    }
}

// K3: single block: pooled mean, 16x64 @ 64x128, BatchNorm (biased), ReLU.
__global__ __launch_bounds__(256) void k_mlp(const float* __restrict__ seg_sum,
                                             const int* __restrict__ bnd,
                                             const float* __restrict__ W,
                                             const float* __restrict__ gamma,
                                             const float* __restrict__ beta,
                                             float* __restrict__ h_final) {
    __shared__ float pooled[NSEG * CIN];
    __shared__ float h_lds[NSEG * COUT];
    __shared__ float cnt[NSEG];
    __shared__ float scale_s[COUT], bias_s[COUT];
    const int tid = threadIdx.x;

    if (tid < NSEG) cnt[tid] = (float)max(bnd[tid + 1] - bnd[tid], 1);
    __syncthreads();
    for (int i = tid; i < NSEG * CIN; i += 256) pooled[i] = seg_sum[i] / cnt[i / CIN];
    __syncthreads();

    const int co = tid & 127;
    const int half = tid >> 7;
    float w[CIN];
    #pragma unroll
    for (int c = 0; c < CIN; c += 4)
        *(vf4*)(w + c) = *(const vf4*)(W + (size_t)co * CIN + c);
    for (int b = half; b < NSEG; b += 2) {
        float a = 0.f;
        #pragma unroll
        for (int c = 0; c < CIN; ++c) a += pooled[b * CIN + c] * w[c];
        h_lds[b * COUT + co] = a;
    }
    __syncthreads();

    if (tid < COUT) {
        float m = 0.f;
        #pragma unroll
        for (int b = 0; b < NSEG; ++b) m += h_lds[b * COUT + tid];
        m *= (1.0f / NSEG);
        float v = 0.f;
        #pragma unroll
        for (int b = 0; b < NSEG; ++b) {
            const float d = h_lds[b * COUT + tid] - m;
            v += d * d;
        }
        v *= (1.0f / NSEG);
        const float sc = gamma[tid] * rsqrtf(v + BN_EPS);
        scale_s[tid] = sc;
        bias_s[tid] = beta[tid] - m * sc;
    }
    __syncthreads();
    for (int b = half; b < NSEG; b += 2) {
        const float hv = h_lds[b * COUT + co] * scale_s[co] + bias_s[co];
        h_final[b * COUT + co] = fmaxf(hv, 0.0f);
    }
}

// K4: gather = 16 contiguous broadcast runs. Inner loop: pure nontemporal
// stores of a register-held float4 pattern; reload pattern only at segment
// boundary crossings (<=15 total across the whole grid per lane phase).
__global__ __launch_bounds__(256) void k_gather(const float* __restrict__ h_final,
                                                const int* __restrict__ bnd,
                                                float* __restrict__ out,
                                                int N, int rows_per_blk) {
    __shared__ vf4 h4[NSEG * 32];
    __shared__ int sbnd[NSEG + 1];
    const int tid = threadIdx.x;
    if (tid <= NSEG) sbnd[tid] = bnd[tid];
    for (int i = tid; i < NSEG * 32; i += 256) h4[i] = ((const vf4*)h_final)[i];
    __syncthreads();

    const int row0 = blockIdx.x * rows_per_blk;
    const int row_end = min(row0 + rows_per_blk, N);
    if (row0 >= row_end) return;

    const int q = tid & 31;       // float4 within row
    const int rofs = tid >> 5;    // 0..7
    int r = row0 + rofs;
    int s = 0;
    while (s < NSEG - 1 && sbnd[s + 1] <= r) ++s;
    vf4 pat = h4[s * 32 + q];
    int nb = sbnd[s + 1];
    vf4* out4 = (vf4*)out;
    for (; r < row_end; r += 8) {
        while (r >= nb) { ++s; nb = sbnd[s + 1]; pat = h4[s * 32 + q]; }
        __builtin_nontemporal_store(pat, &out4[(size_t)r * 32 + q]);
    }
}

extern "C" void kernel_launch(void* const* d_in, const int* in_sizes, int n_in,
                              void* d_out, int out_size, void* d_ws, size_t ws_size,
                              hipStream_t stream) {
    const float* feat  = (const float*)d_in[0];
    const float* W     = (const float*)d_in[1];
    const float* gamma = (const float*)d_in[2];
    const float* beta  = (const float*)d_in[3];
    const void*  idx   = d_in[4];
    const int N = in_sizes[4];

    float* seg_sum = (float*)d_ws;
    float* h_final = (float*)d_ws + NSEG * CIN;
    int*   bnd     = (int*)((float*)d_ws + NSEG * CIN + NSEG * COUT);

    hipLaunchKernelGGL(k_bounds, dim3(1), dim3(256), 0, stream, idx, N, seg_sum, bnd);

    const int NB1 = 1024;
    const int rpb1 = (((N + NB1 - 1) / NB1) + 15) & ~15;
    hipLaunchKernelGGL(k_segsum, dim3(NB1), dim3(256), 0, stream,
                       feat, bnd, seg_sum, N, rpb1);

    hipLaunchKernelGGL(k_mlp, dim3(1), dim3(256), 0, stream,
                       seg_sum, bnd, W, gamma, beta, h_final);

    const int NB2 = 2048;
    const int rpb2 = (((N + NB2 - 1) / NB2) + 7) & ~7;
    const int nb2 = (N + rpb2 - 1) / rpb2;
    hipLaunchKernelGGL(k_gather, dim3(nb2), dim3(256), 0, stream,
                       h_final, bnd, (float*)d_out, N, rpb2);
}